// Round 3
// baseline (1295.610 us; speedup 1.0000x reference)
//
#include <hip/hip_runtime.h>
#include <math.h>

typedef _Float16 f16;
typedef _Float16 f16x8 __attribute__((ext_vector_type(8)));
typedef float    f32x4 __attribute__((ext_vector_type(4)));

#define MFMA16(A, B, C) __builtin_amdgcn_mfma_f32_16x16x32_f16((A), (B), (C), 0, 0, 0)
#define LOG2E 1.44269504088896f

// Weights/biases pre-scaled by -log2e (sigmoid) or -2*log2e (g gate):
// sigma(z) = rcp(1 + 2^acc) with a bare v_exp_f32.
__device__ __forceinline__ float sig2(float a) {
    return __builtin_amdgcn_rcpf(1.0f + __builtin_amdgcn_exp2f(a));
}
__device__ __forceinline__ float tanh2(float c) {
    return fmaf(2.0f, sig2(c * (-2.0f * LOG2E)), -1.0f);
}

__device__ __forceinline__ f16x8 ldfrag(const float* __restrict__ W, int n, int k0, float s) {
    const float* p = W + (size_t)n * 64 + k0;
    f16x8 r;
#pragma unroll
    for (int j = 0; j < 8; j++) r[j] = (f16)(s * p[j]);
    return r;
}

// ---- LDS flag sync (replaces s_barrier in steady loops) ----
// Producer: data ds_writes; s_waitcnt lgkmcnt(0); flag store (lane 0).
// Consumer: poll flags (volatile) until >= want; compiler fence; data reads.
// LDS is physically shared + per-wave in-order -> flag>=want implies the
// producer's data writes are committed and visible. Bounded spin: a logic
// bug fails the reference check instead of hanging the harness.
__device__ __forceinline__ void poll4(volatile unsigned* f, unsigned want) {
    int g = 0;
    for (;;) {
        unsigned a = f[0], b = f[1], c = f[2], d = f[3];
        if ((a >= want) & (b >= want) & (c >= want) & (d >= want)) break;
        if (++g > (1 << 22)) break;
    }
    asm volatile("" ::: "memory");
}
__device__ __forceinline__ void poll44(volatile unsigned* f, unsigned wa, unsigned wb) {
    int g = 0;
    for (;;) {
        unsigned a = f[0], b = f[1], c = f[2], d = f[3];
        unsigned e = f[4], h = f[5], i = f[6], j = f[7];
        if ((a >= wa) & (b >= wa) & (c >= wa) & (d >= wa) &
            (e >= wb) & (h >= wb) & (i >= wb) & (j >= wb)) break;
        if (++g > (1 << 22)) break;
    }
    asm volatile("" ::: "memory");
}
__device__ __forceinline__ void publish(volatile unsigned* f, int idx, unsigned v, bool doit) {
    asm volatile("s_waitcnt lgkmcnt(0)" ::: "memory");
    if (doit) f[idx] = v;
}

// One block per BATCH PAIR; 512 threads = 8 waves, layer-specialized:
// waves 0-3 ("A") = encoder L1 / decoder dec1; waves 4-7 ("B") = encoder L2 /
// decoder dec2. Flags: flg[0..3]=Ae (enc L1 ticks done per A-wave),
// [4..7]=Be, [8..11]=Ad (dec1 steps), [12..15]=Bd (dec2 steps).
// h1l/h2l are 4-deep rings for elastic A/B decoupling.
__global__ __launch_bounds__(512, 2)
void seq2seq_kernel(const float* __restrict__ src, const float* __restrict__ trg,
                    const float* __restrict__ e1ih, const float* __restrict__ e1hh,
                    const float* __restrict__ e1b,
                    const float* __restrict__ e2ih, const float* __restrict__ e2hh,
                    const float* __restrict__ e2b,
                    const float* __restrict__ d1ih, const float* __restrict__ d1hh,
                    const float* __restrict__ d1b,
                    const float* __restrict__ d2ih, const float* __restrict__ d2hh,
                    const float* __restrict__ d2b,
                    const float* __restrict__ fcW, const float* __restrict__ fcb,
                    float* __restrict__ out)
{
    const int bp   = blockIdx.x;
    const int tid  = threadIdx.x;
    const int wv   = tid >> 6;               // 0..7
    const bool isB = (wv >= 4);
    const int wvg  = wv & 3;
    const int lane = tid & 63;
    const int quad = lane >> 4;
    const int c15  = lane & 15;
    const int u16  = wvg * 16 + c15;
    const int qb   = quad & 1;               // batch this lane's activations
    const int ab   = c15 & 1;                // batch this lane's A-row feeds

    __shared__ __align__(16) float xst[1024][8];   // [t][bat*4+c] src, 32 KB
    __shared__ __align__(16) float tst[512][8];    // trg, 16 KB
    __shared__ __align__(16) f16 h1l[4][2][64];    // [slot][bat][u], 4-deep ring
    __shared__ __align__(16) f16 h2l[4][2][64];
    __shared__ float c1buf[2][64];                 // dec1 cell out (A -> B)
    __shared__ float c2buf[2][64];                 // dec2 cell out (B -> A)
    __shared__ __align__(16) f16 ring[2][16][72];  // [bat][step&15][u] h2 history
    __shared__ unsigned flg[16];

    volatile unsigned* vflg = flg;

    // ---- one-time staging of src/trg into LDS ----
    {
        const float* s0 = src + (size_t)(2 * bp) * 3072;
        const float* s1 = s0 + 3072;
        for (int i = tid; i < 3072; i += 512) {
            int t = i / 3, c = i - 3 * t;
            xst[t][c]     = s0[i];
            xst[t][4 + c] = s1[i];
        }
        const float* t0p = trg + (size_t)(2 * bp) * 1536;
        const float* t1p = t0p + 1536;
        for (int i = tid; i < 1536; i += 512) {
            int t = i / 3, c = i - 3 * t;
            tst[t][c]     = t0p[i];
            tst[t][4 + c] = t1p[i];
        }
    }

    // ---- group-specialized encoder weights ----
    f16x8 E1hh[4][2];                        // A only
    f16x8 E2ih[4][2], E2hh[4][2];            // B only
    float xw[4][3], bias1[4];
    f32x4 bs2[4];                            // B: bias2 splat (MFMA C-init)
    if (!isB) {
#pragma unroll
        for (int g = 0; g < 4; g++) {
            const float s = (g == 2) ? (-2.0f * LOG2E) : (-LOG2E);
            const int n = g * 64 + u16;
#pragma unroll
            for (int c = 0; c < 2; c++)
                E1hh[g][c] = ldfrag(e1hh, n, c * 32 + quad * 8, s);
            xw[g][0] = s * e1ih[n * 3 + 0];
            xw[g][1] = s * e1ih[n * 3 + 1];
            xw[g][2] = s * e1ih[n * 3 + 2];
            bias1[g] = s * e1b[n];
        }
    } else {
#pragma unroll
        for (int g = 0; g < 4; g++) {
            const float s = (g == 2) ? (-2.0f * LOG2E) : (-LOG2E);
            const int n = g * 64 + u16;
#pragma unroll
            for (int c = 0; c < 2; c++) {
                E2ih[g][c] = ldfrag(e2ih, n, c * 32 + quad * 8, s);
                E2hh[g][c] = ldfrag(e2hh, n, c * 32 + quad * 8, s);
            }
            float bv = s * e2b[n];
            bs2[g] = (f32x4){bv, bv, bv, bv};
        }
    }

    float c1 = 0.f, c2 = 0.f;
    if (tid < 512) {                          // zero ALL ring slots (initial h = 0)
        (&h1l[0][0][0])[tid] = (f16)0.f;
        (&h2l[0][0][0])[tid] = (f16)0.f;
    }
    if (tid < 16) flg[tid] = 0;
    __syncthreads();

    const f32x4 z4 = {0.f, 0.f, 0.f, 0.f};

    // ---------------- encoder: flag-synced free-running loops --------------
    if (!isB) {
        // L1: h1(tau) = f(h1(tau-1), x(tau)); h1(k) -> h1l[k&3]
#pragma unroll 1
        for (unsigned tau = 0; tau < 1024; tau++) {
            f32x4 xq = *(const f32x4*)&xst[tau][qb * 4];   // read-only, no sync
            // Ae>=tau: own-group h1(tau-1) ready. Be>=tau-3: B consumed the
            // slot (tau&3) we are about to overwrite (B@tau-3 read h1(tau-4)).
            poll44(vflg, tau, tau >= 3 ? tau - 3 : 0);
            const f16* h1p = h1l[(tau + 3) & 3][ab];
            f16x8 a0 = *(const f16x8*)(h1p + quad * 8);
            f16x8 a1 = *(const f16x8*)(h1p + 32 + quad * 8);
            float xt[4];
#pragma unroll
            for (int g = 0; g < 4; g++)
                xt[g] = fmaf(xw[g][0], xq.x,
                        fmaf(xw[g][1], xq.y, fmaf(xw[g][2], xq.z, bias1[g])));
            f32x4 acc[4];
#pragma unroll
            for (int g = 0; g < 4; g++)
                acc[g] = MFMA16(a1, E1hh[g][1], MFMA16(a0, E1hh[g][0], z4));
            float v[4];
#pragma unroll
            for (int g = 0; g < 4; g++)
                v[g] = (qb ? acc[g][1] : acc[g][0]) + xt[g];
            float iv = sig2(v[0]), fv = sig2(v[1]);
            float gv = fmaf(2.0f, sig2(v[2]), -1.0f), ov = sig2(v[3]);
            c1 = fv * c1 + iv * gv;
            if (quad < 2) h1l[tau & 3][quad][u16] = (f16)(ov * tanh2(c1));
            publish(vflg, wvg, tau + 1, lane == 0);
        }
    } else {
        // L2 at tick tau computes h2(tau-1) = f(h1(tau-1), h2(tau-2));
        // h2(k) -> h2l[k&3]
#pragma unroll 1
        for (unsigned tau = 1; tau <= 1024; tau++) {
            // Ae>=tau: h1(tau-1) ready. Be>=tau-1: all B-waves wrote h2(tau-2)
            // (also covers overwrite of slot (tau-1)&3, last read by B@tau-3).
            poll44(vflg, tau, tau - 1);
            const f16* h1p = h1l[(tau + 3) & 3][ab];
            const f16* h2p = h2l[(tau + 2) & 3][ab];
            f16x8 a0 = *(const f16x8*)(h1p + quad * 8);
            f16x8 a1 = *(const f16x8*)(h1p + 32 + quad * 8);
            f16x8 b0 = *(const f16x8*)(h2p + quad * 8);
            f16x8 b1 = *(const f16x8*)(h2p + 32 + quad * 8);
            f32x4 accA[4], accB[4];
#pragma unroll
            for (int g = 0; g < 4; g++) {
                accA[g] = MFMA16(a1, E2ih[g][1], MFMA16(a0, E2ih[g][0], bs2[g]));
                accB[g] = MFMA16(b1, E2hh[g][1], MFMA16(b0, E2hh[g][0], z4));
            }
            float v[4];
#pragma unroll
            for (int g = 0; g < 4; g++)
                v[g] = (qb ? accA[g][1] : accA[g][0]) +
                       (qb ? accB[g][1] : accB[g][0]);
            float iv = sig2(v[0]), fv = sig2(v[1]);
            float gv = fmaf(2.0f, sig2(v[2]), -1.0f), ov = sig2(v[3]);
            c2 = fv * c2 + iv * gv;
            if (quad < 2) h2l[(tau + 3) & 3][quad][u16] = (f16)(ov * tanh2(c2));
            publish(vflg + 4, wvg, tau, lane == 0);
        }
    }
    // h2(1023) in h2l[3]; c2 in B registers

    // ---------------- decoder weights (group-specialized) -------------------
    f16x8 D1hh[4][2];                        // A
    f16x8 W2s[4][2];                         // B
    float dxw[4][3], db1[4];
    f32x4 db2s[4];                           // B: dec2 bias splat (C-init)
    f16x8 FW0 = {}, FW1 = {};
    float fb = 0.f;
    if (!isB) {
#pragma unroll
        for (int g = 0; g < 4; g++) {
            const float s = (g == 2) ? (-2.0f * LOG2E) : (-LOG2E);
            const int n = g * 64 + u16;
#pragma unroll
            for (int c = 0; c < 2; c++)
                D1hh[g][c] = ldfrag(d1hh, n, c * 32 + quad * 8, s);
            dxw[g][0] = s * d1ih[n * 3 + 0];
            dxw[g][1] = s * d1ih[n * 3 + 1];
            dxw[g][2] = s * d1ih[n * 3 + 2];
            db1[g] = s * d1b[n];
        }
    } else {
#pragma unroll
        for (int g = 0; g < 4; g++) {
            const float s = (g == 2) ? (-2.0f * LOG2E) : (-LOG2E);
            const int n = g * 64 + u16;
#pragma unroll
            for (int c = 0; c < 2; c++) {
                const int k0 = c * 32 + quad * 8;
                const float* pa = d2ih + (size_t)n * 64 + k0;
                const float* pb = d2hh + (size_t)n * 64 + k0;
                f16x8 r2;
#pragma unroll
                for (int j = 0; j < 8; j++) r2[j] = (f16)(s * (pa[j] + pb[j]));
                W2s[g][c] = r2;
            }
            float bv = s * d2b[n];
            db2s[g] = (f32x4){bv, bv, bv, bv};
        }
        // seed c2buf with encoder final c2 (A reads it at t=0)
        if (quad < 2) c2buf[quad][u16] = c2;
        // FC: register B-fragments of fcW^T (waves 6-7), B[k][n]=fcW[n][k]
        if (wv >= 6 && c15 < 3) {
#pragma unroll
            for (int j = 0; j < 8; j++) {
                FW0[j] = (f16)fcW[c15 * 64 + quad * 8 + j];
                FW1[j] = (f16)fcW[c15 * 64 + 32 + quad * 8 + j];
            }
            fb = fcb[c15];
        }
        // reset dec flags happens above (flg[8..15] still 0 - untouched)
    }
    __syncthreads();   // fences c2buf seed + h2l[3]; dec flags are zero

    // ---------------- decoder: flag-synced serial chain ---------------------
    // step t: A: dec1(t) <- h2d(t-1)[h2l[(t-1)&3]], c2(t-1)[c2buf]
    //         B: dec2(t) <- h1d(t)[h1l[t&3]], c1(t)[c1buf]; writes h2l[t&3]
    if (!isB) {
#pragma unroll 1
        for (unsigned t = 0; t < 511; t++) {
            f32x4 tq = *(const f32x4*)&tst[t][qb * 4];   // read-only
            poll4(vflg + 12, t);                          // Bd>=t: h2d/c2 of t-1
            const f16* hp = h2l[(t + 3) & 3][ab];
            f16x8 a0 = *(const f16x8*)(hp + quad * 8);
            f16x8 a1 = *(const f16x8*)(hp + 32 + quad * 8);
            float cdin = c2buf[qb][u16];
            float xt[4];
#pragma unroll
            for (int g = 0; g < 4; g++)
                xt[g] = fmaf(dxw[g][0], tq.x,
                        fmaf(dxw[g][1], tq.y, fmaf(dxw[g][2], tq.z, db1[g])));
            f32x4 acc[4];
#pragma unroll
            for (int g = 0; g < 4; g++)
                acc[g] = MFMA16(a1, D1hh[g][1], MFMA16(a0, D1hh[g][0], z4));
            float v[4];
#pragma unroll
            for (int g = 0; g < 4; g++)
                v[g] = (qb ? acc[g][1] : acc[g][0]) + xt[g];
            float iv = sig2(v[0]), fv = sig2(v[1]);
            float gv = fmaf(2.0f, sig2(v[2]), -1.0f), ov = sig2(v[3]);
            float c1d = fv * cdin + iv * gv;
            if (quad < 2) {
                h1l[t & 3][quad][u16] = (f16)(ov * tanh2(c1d));
                c1buf[quad][u16]  = c1d;
            }
            publish(vflg + 8, wvg, t + 1, lane == 0);
        }
    } else {
#pragma unroll 1
        for (unsigned t = 0; t < 511; t++) {
            if (wv >= 6 && t > 0 && (t & 15) == 0) {
                // ---- batched FC for steps t-16..t-1 (2 MFMAs) ----
                poll4(vflg + 12, t);                      // all B ring writes done
                const int bsel = wv - 6;
                const f16* rp = &ring[bsel][0][0];
                f16x8 fa0 = *(const f16x8*)(rp + c15 * 72 + quad * 8);
                f16x8 fa1 = *(const f16x8*)(rp + c15 * 72 + 32 + quad * 8);
                f32x4 acc = MFMA16(fa1, FW1, MFMA16(fa0, FW0, z4));
                if (c15 < 3) {
                    float* ob = out + (((size_t)(2 * bp + bsel) * 512 + (t - 15)) * 3) + c15;
#pragma unroll
                    for (int rg = 0; rg < 4; rg++)
                        ob[(quad * 4 + rg) * 3] = acc[rg] + fb;
                }
            }
            poll4(vflg + 8, t + 1);                       // Ad>=t+1: h1d(t), c1(t)
            const f16* np = h1l[t & 3][ab];
            f16x8 m0 = *(const f16x8*)(np + quad * 8);
            f16x8 m1 = *(const f16x8*)(np + 32 + quad * 8);
            float c1in = c1buf[qb][u16];
            f32x4 acc[4];
#pragma unroll
            for (int g = 0; g < 4; g++)
                acc[g] = MFMA16(m1, W2s[g][1], MFMA16(m0, W2s[g][0], db2s[g]));
            float v[4];
#pragma unroll
            for (int g = 0; g < 4; g++)
                v[g] = (qb ? acc[g][1] : acc[g][0]);
            float i2 = sig2(v[0]), f2 = sig2(v[1]);
            float g2 = fmaf(2.0f, sig2(v[2]), -1.0f), o2 = sig2(v[3]);
            float c2d = f2 * c1in + i2 * g2;
            if (quad < 2) {
                f16 hh = (f16)(o2 * tanh2(c2d));
                h2l[t & 3][quad][u16] = hh;
                c2buf[quad][u16]  = c2d;
                ring[quad][t & 15][u16] = hh;   // FC history
            }
            publish(vflg + 12, wvg, t + 1, lane == 0);
        }
        // drain: FC for steps 496..510 (ring slots 0..14) -> rows 497..511
        if (wv >= 6) {
            poll4(vflg + 12, 511);
            const int bsel = wv - 6;
            const f16* rp = &ring[bsel][0][0];
            f16x8 fa0 = *(const f16x8*)(rp + c15 * 72 + quad * 8);
            f16x8 fa1 = *(const f16x8*)(rp + c15 * 72 + 32 + quad * 8);
            f32x4 acc = MFMA16(fa1, FW1, MFMA16(fa0, FW0, z4));
            if (c15 < 3) {
                float* ob = out + (((size_t)(2 * bp + bsel) * 512 + 497) * 3) + c15;
#pragma unroll
                for (int rg = 0; rg < 4; rg++) {
                    int step = quad * 4 + rg;
                    if (step < 15) ob[step * 3] = acc[rg] + fb;
                }
            }
        }
    }
}

extern "C" void kernel_launch(void* const* d_in, const int* in_sizes, int n_in,
                              void* d_out, int out_size, void* d_ws, size_t ws_size,
                              hipStream_t stream)
{
    const float* src   = (const float*)d_in[0];
    const float* trg   = (const float*)d_in[1];
    const float* e1ih  = (const float*)d_in[2];
    const float* e1hh  = (const float*)d_in[3];
    const float* e1b   = (const float*)d_in[4];
    const float* e2ih  = (const float*)d_in[5];
    const float* e2hh  = (const float*)d_in[6];
    const float* e2b   = (const float*)d_in[7];
    const float* dd1ih = (const float*)d_in[8];
    const float* dd1hh = (const float*)d_in[9];
    const float* dd1b  = (const float*)d_in[10];
    const float* dd2ih = (const float*)d_in[11];
    const float* dd2hh = (const float*)d_in[12];
    const float* dd2b  = (const float*)d_in[13];
    const float* fcW   = (const float*)d_in[14];
    const float* fcb   = (const float*)d_in[15];
    float* out = (float*)d_out;

    // outputs[:, 0, :] stays 0; decoder fills t >= 1
    hipMemsetAsync(d_out, 0, (size_t)out_size * sizeof(float), stream);

    seq2seq_kernel<<<256, 512, 0, stream>>>(src, trg,
                                            e1ih, e1hh, e1b, e2ih, e2hh, e2b,
                                            dd1ih, dd1hh, dd1b, dd2ih, dd2hh, dd2b,
                                            fcW, fcb, out);
}